// Round 1
// baseline (153.565 us; speedup 1.0000x reference)
//
#include <hip/hip_runtime.h>
#include <hip/hip_bf16.h>

// ProtoNet LOO loss on MI355X.
// Algebra: logit[q,k] = xq·p[k] - 0.5||p[k]||^2 - 0.5||xq||^2 (non-LOO),
// with a closed-form leave-one-out fix for k* = ys[pos[q]] derived from the
// same dot/pnorm/qnorm/count (no extra memory traffic).

#define NQ_ 2048
#define NS_ 65536
#define K_  512
#define D_  128
#define CAP_ 160   // per-class row-list capacity (actual count is exactly 128)
#define QB_ 8      // queries per block in the loss kernel

// ---------------------------------------------------------------- bucket ----
__global__ void bucket_kernel(const int* __restrict__ ys,
                              int* __restrict__ counts,
                              int* __restrict__ list) {
    int s = blockIdx.x * blockDim.x + threadIdx.x;
    if (s < NS_) {
        int c = ys[s];
        int slot = atomicAdd(&counts[c], 1);
        if (slot < CAP_) list[c * CAP_ + slot] = s;
    }
}

// ----------------------------------------------------------------- proto ----
// One block (128 threads = 2 waves) per class: gather member rows coalesced,
// sum, divide by max(cnt,0.1), write p[k][d] and pnorm[k] = ||p[k]||^2.
__global__ void proto_kernel(const float* __restrict__ xs,
                             const int* __restrict__ counts,
                             const int* __restrict__ list,
                             float* __restrict__ p,
                             float* __restrict__ pnorm) {
    int k = blockIdx.x;
    int d = threadIdx.x;           // 0..127
    __shared__ int idx_s[CAP_];
    __shared__ float red_s[2];

    int cnt = counts[k];
    int m = min(cnt, CAP_);
    for (int i = d; i < CAP_; i += 128) idx_s[i] = (i < m) ? list[k * CAP_ + i] : 0;
    __syncthreads();

    float acc = 0.f;
    int r = 0;
    // 8-deep independent gather loads to hide HBM latency
    for (; r + 8 <= m; r += 8) {
        int i0 = idx_s[r+0], i1 = idx_s[r+1], i2 = idx_s[r+2], i3 = idx_s[r+3];
        int i4 = idx_s[r+4], i5 = idx_s[r+5], i6 = idx_s[r+6], i7 = idx_s[r+7];
        float v0 = xs[i0 * D_ + d]; float v1 = xs[i1 * D_ + d];
        float v2 = xs[i2 * D_ + d]; float v3 = xs[i3 * D_ + d];
        float v4 = xs[i4 * D_ + d]; float v5 = xs[i5 * D_ + d];
        float v6 = xs[i6 * D_ + d]; float v7 = xs[i7 * D_ + d];
        acc += ((v0 + v1) + (v2 + v3)) + ((v4 + v5) + (v6 + v7));
    }
    for (; r < m; ++r) acc += xs[idx_s[r] * D_ + d];

    float cf = (float)cnt;
    float pv = acc / fmaxf(cf, 0.1f);
    p[k * D_ + d] = pv;

    // block reduction of pv^2 over 128 threads (2 waves)
    float sq = pv * pv;
    #pragma unroll
    for (int off = 32; off; off >>= 1) sq += __shfl_down(sq, off, 64);
    int wave = d >> 6, lane = d & 63;
    if (lane == 0) red_s[wave] = sq;
    __syncthreads();
    if (d == 0) pnorm[k] = red_s[0] + red_s[1];
}

// ------------------------------------------------------------------ loss ----
__device__ inline float logit_of(float dot, float pn, float cnt, float qn, bool loo) {
    if (!loo) {
        if (cnt <= 0.1f) return 0.f;              // mask (C = cnt)
        return dot - 0.5f * pn - 0.5f * qn;
    }
    float cm1 = cnt - 1.f;
    if (cm1 <= 0.1f) return 0.f;                  // mask (C = cnt-1)
    float dotM = cnt * dot;                        // xq·mus
    float msq  = cnt * cnt * pn;                   // ||mus||^2
    float xp   = (dotM - qn) / cm1;                // xq·p_loo
    float plsq = (msq - 2.f * dotM + qn) / (cm1 * cm1);
    return xp - 0.5f * plsq - 0.5f * qn;
}

__launch_bounds__(256)
__global__ void loss_kernel(const float* __restrict__ xq,
                            const int* __restrict__ ys,
                            const int* __restrict__ pos,
                            const float* __restrict__ p,
                            const float* __restrict__ pnorm,
                            const int* __restrict__ counts,
                            float* __restrict__ out) {
    __shared__ float xq_s[QB_][D_];
    __shared__ float logit_s[QB_][K_];
    __shared__ float qn_s[QB_];
    __shared__ int   ks_s[QB_];

    int t  = threadIdx.x;           // 0..255
    int q0 = blockIdx.x * QB_;

    // stage xq tile (8 rows x 128) via float4; fuse ||xq||^2 (32 lanes/query)
    {
        const float4* src = (const float4*)(xq + q0 * D_);
        float4 v = src[t];
        ((float4*)&xq_s[0][0])[t] = v;
        float s = v.x*v.x + v.y*v.y + v.z*v.z + v.w*v.w;
        #pragma unroll
        for (int off = 16; off; off >>= 1) s += __shfl_down(s, off, 32);
        if ((t & 31) == 0) qn_s[t >> 5] = s;
    }
    if (t < QB_) ks_s[t] = ys[pos[q0 + t]];
    __syncthreads();

    // each thread owns classes k0=t, k1=t+256; dot vs 8 queries from LDS
    float acc0[QB_], acc1[QB_];
    #pragma unroll
    for (int q = 0; q < QB_; ++q) { acc0[q] = 0.f; acc1[q] = 0.f; }
    int k0 = t, k1 = t + 256;
    const float4* p4  = (const float4*)p;
    const float4* xs4 = (const float4*)&xq_s[0][0];
    #pragma unroll 4
    for (int d4 = 0; d4 < D_/4; ++d4) {
        float4 pa = p4[k0 * (D_/4) + d4];
        float4 pb = p4[k1 * (D_/4) + d4];
        #pragma unroll
        for (int q = 0; q < QB_; ++q) {
            float4 xv = xs4[q * (D_/4) + d4];
            acc0[q] += pa.x*xv.x + pa.y*xv.y + pa.z*xv.z + pa.w*xv.w;
            acc1[q] += pb.x*xv.x + pb.y*xv.y + pb.z*xv.z + pb.w*xv.w;
        }
    }

    float pn0 = pnorm[k0], pn1 = pnorm[k1];
    float c0 = (float)counts[k0], c1 = (float)counts[k1];
    #pragma unroll
    for (int q = 0; q < QB_; ++q) {
        float qn = qn_s[q];
        int   ks = ks_s[q];
        logit_s[q][k0] = logit_of(acc0[q], pn0, c0, qn, k0 == ks);
        logit_s[q][k1] = logit_of(acc1[q], pn1, c1, qn, k1 == ks);
    }
    __syncthreads();

    // softmax + NLL: wave w handles queries 2w, 2w+1
    int wave = t >> 6, lane = t & 63;
    #pragma unroll
    for (int qq = 0; qq < 2; ++qq) {
        int q = wave * 2 + qq;
        float vals[8];
        float vmax = -1e30f;
        #pragma unroll
        for (int j = 0; j < 8; ++j) {
            vals[j] = logit_s[q][lane + j * 64];
            vmax = fmaxf(vmax, vals[j]);
        }
        #pragma unroll
        for (int off = 32; off; off >>= 1) vmax = fmaxf(vmax, __shfl_xor(vmax, off, 64));
        float se = 0.f;
        #pragma unroll
        for (int j = 0; j < 8; ++j) se += __expf(vals[j] - vmax);
        #pragma unroll
        for (int off = 32; off; off >>= 1) se += __shfl_xor(se, off, 64);
        if (lane == 0) {
            float lse = vmax + __logf(se);        // T = 1.0
            float lk  = logit_s[q][ks_s[q]];
            atomicAdd(out, (lse - lk) * (1.0f / NQ_));
        }
    }
}

// ---------------------------------------------------------------- launch ----
extern "C" void kernel_launch(void* const* d_in, const int* in_sizes, int n_in,
                              void* d_out, int out_size, void* d_ws, size_t ws_size,
                              hipStream_t stream) {
    const float* xq  = (const float*)d_in[0];
    // d_in[1] = yq (unused by the reference beyond its length)
    const float* xs  = (const float*)d_in[2];
    const int*   ys  = (const int*)d_in[3];
    const int*   pos = (const int*)d_in[4];
    float* out = (float*)d_out;

    char* ws = (char*)d_ws;
    int*   counts = (int*)ws;                                   // K_ ints
    int*   list   = (int*)(ws + 4096);                          // K_*CAP_ ints = 320 KiB
    float* p      = (float*)(ws + 4096 + K_*CAP_*4);            // K_*D_ f32 (16B aligned)
    float* pnorm  = (float*)(ws + 4096 + K_*CAP_*4 + K_*D_*4);  // K_ f32

    hipMemsetAsync(counts, 0, K_ * sizeof(int), stream);
    hipMemsetAsync(out, 0, sizeof(float), stream);

    bucket_kernel<<<(NS_ + 255) / 256, 256, 0, stream>>>(ys, counts, list);
    proto_kernel<<<K_, 128, 0, stream>>>(xs, counts, list, p, pnorm);
    loss_kernel<<<NQ_ / QB_, 256, 0, stream>>>(xq, ys, pos, p, pnorm, counts, out);
}

// Round 2
// 144.159 us; speedup vs baseline: 1.0652x; 1.0652x over previous
//
#include <hip/hip_runtime.h>
#include <hip/hip_bf16.h>

// ProtoNet LOO loss on MI355X — round 2.
// logit[q,k] = xq·p[k] - 0.5||p[k]||^2 - 0.5||xq||^2 (non-LOO) with closed-form
// leave-one-out fixup for k* = ys[pos[q]].
// R2 changes: pT transposed layout (lane=class -> coalesced loads), loss kernel
// QB=4 x 512 threads (grid 512, 16 waves/CU), proto 512 threads (16 waves/CU,
// 8-deep gather ILP -> HBM-saturating).

#define NQ_ 2048
#define NS_ 65536
#define K_  512
#define D_  128
#define CAP_ 160   // per-class row-list capacity (actual count is exactly 128)
#define QB_ 4      // queries per block in the loss kernel

// ---------------------------------------------------------------- bucket ----
__global__ void bucket_kernel(const int* __restrict__ ys,
                              int* __restrict__ counts,
                              int* __restrict__ list) {
    int s = blockIdx.x * blockDim.x + threadIdx.x;
    if (s < NS_) {
        int c = ys[s];
        int slot = atomicAdd(&counts[c], 1);
        if (slot < CAP_) list[c * CAP_ + slot] = s;
    }
}

// ----------------------------------------------------------------- proto ----
// One block (512 threads = 8 waves) per class: 4 row-groups x 128 dims.
// Gather member rows coalesced, sum, divide, write pT[d][k] and pnorm[k].
__global__ void proto_kernel(const float* __restrict__ xs,
                             const int* __restrict__ counts,
                             const int* __restrict__ list,
                             float* __restrict__ pT,
                             float* __restrict__ pnorm) {
    int k = blockIdx.x;
    int t = threadIdx.x;           // 0..511
    int d = t & 127;               // dim
    int h = t >> 7;                // row-group 0..3
    __shared__ int   idx_s[CAP_];
    __shared__ float part_s[4][128];
    __shared__ float red_s[2];

    int cnt = counts[k];
    int m = min(cnt, CAP_);
    if (t < CAP_) idx_s[t] = (t < m) ? list[k * CAP_ + t] : 0;
    __syncthreads();

    int r0 = (m * h) >> 2, r1 = (m * (h + 1)) >> 2;
    float acc = 0.f;
    int r = r0;
    for (; r + 8 <= r1; r += 8) {           // 8-deep independent HBM gathers
        int i0 = idx_s[r+0], i1 = idx_s[r+1], i2 = idx_s[r+2], i3 = idx_s[r+3];
        int i4 = idx_s[r+4], i5 = idx_s[r+5], i6 = idx_s[r+6], i7 = idx_s[r+7];
        float v0 = xs[i0 * D_ + d]; float v1 = xs[i1 * D_ + d];
        float v2 = xs[i2 * D_ + d]; float v3 = xs[i3 * D_ + d];
        float v4 = xs[i4 * D_ + d]; float v5 = xs[i5 * D_ + d];
        float v6 = xs[i6 * D_ + d]; float v7 = xs[i7 * D_ + d];
        acc += ((v0 + v1) + (v2 + v3)) + ((v4 + v5) + (v6 + v7));
    }
    for (; r < r1; ++r) acc += xs[idx_s[r] * D_ + d];
    part_s[h][d] = acc;
    __syncthreads();

    if (t < 128) {
        float s  = (part_s[0][d] + part_s[1][d]) + (part_s[2][d] + part_s[3][d]);
        float pv = s / fmaxf((float)cnt, 0.1f);
        pT[d * K_ + k] = pv;                 // transposed store
        float sq = pv * pv;
        #pragma unroll
        for (int off = 32; off; off >>= 1) sq += __shfl_down(sq, off, 64);
        if ((d & 63) == 0) red_s[d >> 6] = sq;
    }
    __syncthreads();
    if (t == 0) pnorm[k] = red_s[0] + red_s[1];
}

// ------------------------------------------------------------------ loss ----
__device__ inline float logit_of(float dot, float pn, float cnt, float qn, bool loo) {
    if (!loo) {
        if (cnt <= 0.1f) return 0.f;              // mask (C = cnt)
        return dot - 0.5f * pn - 0.5f * qn;
    }
    float cm1 = cnt - 1.f;
    if (cm1 <= 0.1f) return 0.f;                  // mask (C = cnt-1)
    float dotM = cnt * dot;                        // xq·mus
    float msq  = cnt * cnt * pn;                   // ||mus||^2
    float xp   = (dotM - qn) / cm1;                // xq·p_loo
    float plsq = (msq - 2.f * dotM + qn) / (cm1 * cm1);
    return xp - 0.5f * plsq - 0.5f * qn;
}

__launch_bounds__(512)
__global__ void loss_kernel(const float* __restrict__ xq,
                            const int* __restrict__ ys,
                            const int* __restrict__ pos,
                            const float* __restrict__ pT,
                            const float* __restrict__ pnorm,
                            const int* __restrict__ counts,
                            float* __restrict__ out) {
    __shared__ float logit_s[QB_][K_];   // 8 KB
    __shared__ float qn_s[QB_];
    __shared__ int   ks_s[QB_];

    int t    = threadIdx.x;              // 0..511; t == class id
    int wave = t >> 6, lane = t & 63;
    int q0   = blockIdx.x * QB_;

    // ||xq||^2: wave w (w<QB_) reduces query q0+w
    if (wave < QB_) {
        const float* xr = xq + (q0 + wave) * D_;
        float a = xr[lane], b = xr[lane + 64];
        float s = a * a + b * b;
        #pragma unroll
        for (int off = 32; off; off >>= 1) s += __shfl_down(s, off, 64);
        if (lane == 0) qn_s[wave] = s;
    }
    if (t < QB_) ks_s[t] = ys[pos[q0 + t]];
    __syncthreads();

    // dot(xq[q], p[k]) for k = t, q = q0..q0+3.
    // pT load: lane = class -> coalesced 256B/wave. xq reads are wave-uniform
    // -> scalar loads.
    float acc0 = 0.f, acc1 = 0.f, acc2 = 0.f, acc3 = 0.f;
    const float* x0 = xq + (q0 + 0) * D_;
    const float* x1 = xq + (q0 + 1) * D_;
    const float* x2 = xq + (q0 + 2) * D_;
    const float* x3 = xq + (q0 + 3) * D_;
    #pragma unroll 8
    for (int d = 0; d < D_; ++d) {
        float pv = pT[d * K_ + t];
        acc0 = fmaf(pv, x0[d], acc0);
        acc1 = fmaf(pv, x1[d], acc1);
        acc2 = fmaf(pv, x2[d], acc2);
        acc3 = fmaf(pv, x3[d], acc3);
    }

    float pn = pnorm[t];
    float cf = (float)counts[t];
    logit_s[0][t] = logit_of(acc0, pn, cf, qn_s[0], t == ks_s[0]);
    logit_s[1][t] = logit_of(acc1, pn, cf, qn_s[1], t == ks_s[1]);
    logit_s[2][t] = logit_of(acc2, pn, cf, qn_s[2], t == ks_s[2]);
    logit_s[3][t] = logit_of(acc3, pn, cf, qn_s[3], t == ks_s[3]);
    __syncthreads();

    // softmax + NLL: wave w < QB_ handles query q0+w over 512 logits
    if (wave < QB_) {
        int q = wave;
        float vals[8];
        float vmax = -1e30f;
        #pragma unroll
        for (int j = 0; j < 8; ++j) {
            vals[j] = logit_s[q][lane + j * 64];
            vmax = fmaxf(vmax, vals[j]);
        }
        #pragma unroll
        for (int off = 32; off; off >>= 1) vmax = fmaxf(vmax, __shfl_xor(vmax, off, 64));
        float se = 0.f;
        #pragma unroll
        for (int j = 0; j < 8; ++j) se += __expf(vals[j] - vmax);
        #pragma unroll
        for (int off = 32; off; off >>= 1) se += __shfl_xor(se, off, 64);
        if (lane == 0) {
            float lse = vmax + __logf(se);        // T = 1.0
            float lk  = logit_s[q][ks_s[q]];
            atomicAdd(out, (lse - lk) * (1.0f / NQ_));
        }
    }
}

// ---------------------------------------------------------------- launch ----
extern "C" void kernel_launch(void* const* d_in, const int* in_sizes, int n_in,
                              void* d_out, int out_size, void* d_ws, size_t ws_size,
                              hipStream_t stream) {
    const float* xq  = (const float*)d_in[0];
    // d_in[1] = yq (unused beyond its length)
    const float* xs  = (const float*)d_in[2];
    const int*   ys  = (const int*)d_in[3];
    const int*   pos = (const int*)d_in[4];
    float* out = (float*)d_out;

    char* ws = (char*)d_ws;
    int*   counts = (int*)ws;                                   // K_ ints
    int*   list   = (int*)(ws + 4096);                          // K_*CAP_ ints
    float* pT     = (float*)(ws + 4096 + K_*CAP_*4);            // D_*K_ f32 (transposed)
    float* pnorm  = (float*)(ws + 4096 + K_*CAP_*4 + K_*D_*4);  // K_ f32

    hipMemsetAsync(counts, 0, K_ * sizeof(int), stream);
    hipMemsetAsync(out, 0, sizeof(float), stream);

    bucket_kernel<<<(NS_ + 255) / 256, 256, 0, stream>>>(ys, counts, list);
    proto_kernel<<<K_, 512, 0, stream>>>(xs, counts, list, pT, pnorm);
    loss_kernel<<<NQ_ / QB_, 512, 0, stream>>>(xq, ys, pos, pT, pnorm, counts, out);
}